// Round 1
// baseline (960.518 us; speedup 1.0000x reference)
//
#include <hip/hip_runtime.h>
#include <math.h>

constexpr int D = 32000;
constexpr int BLOCK = 1024;
constexpr int NW = BLOCK / 64;                    // 16 waves
constexpr int FULL4 = D / (4 * BLOCK);            // 7 full float4 rounds
constexpr int REM_ELEMS = D - FULL4 * 4 * BLOCK;  // 3328
constexpr int REM_THREADS = REM_ELEMS / 4;        // 832 (= 13 waves exactly)
constexpr int CAP = 2048;
constexpr int NITER = 50;

__device__ __forceinline__ float wave_sum(float s) {
#pragma unroll
  for (int o = 32; o > 0; o >>= 1) s += __shfl_xor(s, o, 64);
  return s;
}

__global__ __launch_bounds__(BLOCK, 4)
void sparsemax_bisect_kernel(const float* __restrict__ X,
                             float* __restrict__ Out) {
  __shared__ float s_cand[CAP];
  __shared__ float s_red[NW];
  __shared__ float s_bc[2];
  __shared__ int s_count;

  const int t = threadIdx.x;
  const int lane = t & 63;
  const int wid = t >> 6;
  const long row = blockIdx.x;

  const float* Xr = X + row * (long)D;
  float* Or = Out + row * (long)D;

  if (t == 0) s_count = 0;

  // ---- Load entire row into registers (coalesced float4) ----
  float4 v[FULL4 + 1];
#pragma unroll
  for (int j = 0; j < FULL4; ++j)
    v[j] = *reinterpret_cast<const float4*>(Xr + 4 * t + 4 * BLOCK * j);
  const bool has_rem = (t < REM_THREADS);
  if (has_rem)
    v[FULL4] = *reinterpret_cast<const float4*>(Xr + 4 * BLOCK * FULL4 + 4 * t);
  else
    v[FULL4] = make_float4(-INFINITY, -INFINITY, -INFINITY, -INFINITY);

  // ---- Row max: local -> wave shuffle -> LDS across 16 waves ----
  float m = -INFINITY;
#pragma unroll
  for (int j = 0; j <= FULL4; ++j)
    m = fmaxf(m, fmaxf(fmaxf(v[j].x, v[j].y), fmaxf(v[j].z, v[j].w)));
#pragma unroll
  for (int o = 32; o > 0; o >>= 1) m = fmaxf(m, __shfl_xor(m, o, 64));
  if (lane == 0) s_red[wid] = m;
  __syncthreads();
  float rowmax = s_red[0];
#pragma unroll
  for (int j = 1; j < NW; ++j) rowmax = fmaxf(rowmax, s_red[j]);

  // ---- Gather candidates x > max-1 (only these can ever contribute:
  //      tau_m > tau_lo >= max-1 for all 50 iterations) ----
  const float thresh = rowmax - 1.0f;
#pragma unroll
  for (int j = 0; j <= FULL4; ++j) {
    const float a0 = v[j].x, a1 = v[j].y, a2 = v[j].z, a3 = v[j].w;
    if (a0 > thresh) { int i = atomicAdd(&s_count, 1); if (i < CAP) s_cand[i] = a0; }
    if (a1 > thresh) { int i = atomicAdd(&s_count, 1); if (i < CAP) s_cand[i] = a1; }
    if (a2 > thresh) { int i = atomicAdd(&s_count, 1); if (i < CAP) s_cand[i] = a2; }
    if (a3 > thresh) { int i = atomicAdd(&s_count, 1); if (i < CAP) s_cand[i] = a3; }
  }
  __syncthreads();
  const int n = s_count;  // block-uniform

  float tau, inv;
  if (n <= CAP) {
    // ---- Fast path: wave 0 bisects over the tiny candidate list ----
    if (wid == 0) {
      float tau_lo = rowmax - 1.0f;
      const float tau_hi = rowmax - (1.0f / (float)D);
      float dm = tau_hi - tau_lo;
      float s = 0.0f;
      for (int i = lane; i < n; i += 64) s += fmaxf(s_cand[i] - tau_lo, 0.0f);
      const float f_lo = wave_sum(s) - 1.0f;  // reference keeps f_lo fixed
      float tau_m = tau_lo;
      for (int it = 0; it < NITER; ++it) {
        dm *= 0.5f;
        tau_m = tau_lo + dm;
        float fs = 0.0f;
        for (int i = lane; i < n; i += 64) fs += fmaxf(s_cand[i] - tau_m, 0.0f);
        const float f_m = wave_sum(fs) - 1.0f;
        if (f_m * f_lo >= 0.0f) tau_lo = tau_m;
      }
      float sp = 0.0f;
      for (int i = lane; i < n; i += 64) sp += fmaxf(s_cand[i] - tau_m, 0.0f);
      sp = wave_sum(sp);
      if (lane == 0) { s_bc[0] = tau_m; s_bc[1] = 1.0f / sp; }
    }
    __syncthreads();
    tau = s_bc[0];
    inv = s_bc[1];
  } else {
    // ---- Fallback (never expected on Gaussian input): full block-wide
    //      bisection over the register-resident row ----
    float tau_lo = rowmax - 1.0f;
    const float tau_hi = rowmax - (1.0f / (float)D);
    float dm = tau_hi - tau_lo;

    auto block_fsum = [&](float tt) -> float {
      float s = 0.0f;
#pragma unroll
      for (int j = 0; j <= FULL4; ++j) {
        s += fmaxf(v[j].x - tt, 0.0f);
        s += fmaxf(v[j].y - tt, 0.0f);
        s += fmaxf(v[j].z - tt, 0.0f);
        s += fmaxf(v[j].w - tt, 0.0f);
      }
      s = wave_sum(s);
      __syncthreads();
      if (lane == 0) s_red[wid] = s;
      __syncthreads();
      float tot = s_red[0];
#pragma unroll
      for (int j = 1; j < NW; ++j) tot += s_red[j];
      return tot;
    };

    const float f_lo = block_fsum(tau_lo) - 1.0f;
    float tau_m = tau_lo;
    for (int it = 0; it < NITER; ++it) {
      dm *= 0.5f;
      tau_m = tau_lo + dm;
      const float f_m = block_fsum(tau_m) - 1.0f;
      if (f_m * f_lo >= 0.0f) tau_lo = tau_m;
    }
    const float sp = block_fsum(tau_m);
    tau = tau_m;
    inv = 1.0f / sp;
  }

  // ---- Epilogue: p = max(x - tau, 0) * inv, straight from registers ----
#pragma unroll
  for (int j = 0; j < FULL4; ++j) {
    float4 o4;
    o4.x = fmaxf(v[j].x - tau, 0.0f) * inv;
    o4.y = fmaxf(v[j].y - tau, 0.0f) * inv;
    o4.z = fmaxf(v[j].z - tau, 0.0f) * inv;
    o4.w = fmaxf(v[j].w - tau, 0.0f) * inv;
    *reinterpret_cast<float4*>(Or + 4 * t + 4 * BLOCK * j) = o4;
  }
  if (has_rem) {
    float4 o4;
    o4.x = fmaxf(v[FULL4].x - tau, 0.0f) * inv;
    o4.y = fmaxf(v[FULL4].y - tau, 0.0f) * inv;
    o4.z = fmaxf(v[FULL4].z - tau, 0.0f) * inv;
    o4.w = fmaxf(v[FULL4].w - tau, 0.0f) * inv;
    *reinterpret_cast<float4*>(Or + 4 * BLOCK * FULL4 + 4 * t) = o4;
  }
}

extern "C" void kernel_launch(void* const* d_in, const int* in_sizes, int n_in,
                              void* d_out, int out_size, void* d_ws, size_t ws_size,
                              hipStream_t stream) {
  const float* X = (const float*)d_in[0];
  float* Out = (float*)d_out;
  const int rows = in_sizes[0] / D;
  hipLaunchKernelGGL(sparsemax_bisect_kernel, dim3(rows), dim3(BLOCK), 0, stream,
                     X, Out);
}